// Round 11
// baseline (592.329 us; speedup 1.0000x reference)
//
#include <hip/hip_runtime.h>
#include <hip/hip_bf16.h>
#include <math.h>

// MLA forward. GEMMs: bf16 MFMA 128xBN tile, 2-phase double-buffered LDS
// (stage t+1 before compute t, one barrier per K-step). Attention: bf16 MFMA
// flash with K/V prefetch (T14) + setprio (T5). fp32 accum everywhere.

constexpr int BB  = 2;
constexpr int TT  = 2048;
constexpr int NHH = 16;
constexpr int MM  = BB * TT;
constexpr float QSCALE = 0.07216878364870323f;  // 1/sqrt(192)

typedef __attribute__((ext_vector_type(8))) short short8;
typedef __attribute__((ext_vector_type(16))) float f32x16;

__device__ __forceinline__ unsigned pk2(float lo, float hi) {
  __hip_bfloat162 h = __float22bfloat162_rn(make_float2(lo, hi));
  union { __hip_bfloat162 b; unsigned u; } cv;
  cv.b = h;
  return cv.u;
}
__device__ __forceinline__ ushort bfu(float x) {
  union { __hip_bfloat16 b; ushort u; } cv;
  cv.b = __float2bfloat16(x);
  return cv.u;
}
__device__ __forceinline__ void gload_lds16(const void* g, void* l) {
  __builtin_amdgcn_global_load_lds((const __attribute__((address_space(1))) void*)g,
                                   (__attribute__((address_space(3))) void*)l, 16, 0, 0);
}

// ---------------------------------------------------------------------------
// fp32 -> bf16 flat convert (n % 1024 == 0)
__global__ __launch_bounds__(256) void conv_kernel(const float* __restrict__ src,
                                                   ushort* __restrict__ dst) {
  const size_t i = ((size_t)blockIdx.x * 256 + threadIdx.x) * 4;
  const float4 v = *(const float4*)(src + i);
  uint2 u;
  u.x = pk2(v.x, v.y);
  u.y = pk2(v.z, v.w);
  *(uint2*)(dst + i) = u;
}

// fp32 [K][N] -> bf16 [N][K] transpose-convert. Grid (N/64, K/64), 256 thr.
__global__ __launch_bounds__(256) void tconv_kernel(const float* __restrict__ src,
                                                    ushort* __restrict__ dst,
                                                    int K, int N) {
  __shared__ ushort tile[64][72];
  const int k0 = blockIdx.y * 64, n0 = blockIdx.x * 64;
  const int t = threadIdx.x;
  const int r = t >> 4, c4 = (t & 15) * 4;
#pragma unroll
  for (int p = 0; p < 4; ++p) {
    const int k = r + p * 16;
    const float4 v = *(const float4*)(src + (size_t)(k0 + k) * N + n0 + c4);
    tile[c4 + 0][k] = bfu(v.x);
    tile[c4 + 1][k] = bfu(v.y);
    tile[c4 + 2][k] = bfu(v.z);
    tile[c4 + 3][k] = bfu(v.w);
  }
  __syncthreads();
#pragma unroll
  for (int p = 0; p < 4; ++p) {
    const int n = r + p * 16;
    ushort4 o;
    o.x = tile[n][c4 + 0];
    o.y = tile[n][c4 + 1];
    o.z = tile[n][c4 + 2];
    o.w = tile[n][c4 + 3];
    *(ushort4*)(dst + (size_t)(n0 + n) * K + k0 + c4) = o;
  }
}

// ---------------------------------------------------------------------------
// bf16 MFMA GEMM: C[M][N] = A[M][K] @ Bt[N][K]^T (+bias)(+RoPE)(+scale).
// 128xBN tile, BK=64, 4 waves. 2-phase double-buffered LDS: stage K-tile t+1
// (global_load_lds w16, T2 swizzle via pre-swizzled source) BEFORE computing
// tile t; ONE barrier per K-step (vmcnt drain lands after MFMA issue).
// OM: 0 fp32 out, 1 bf16 out, 2 bf16*QSCALE out. RD: RoPE width (0 = none).
template <int RD, int OM, int BN>
__global__ __launch_bounds__(256, 2) void gemm_mfma_kernel(
    const ushort* __restrict__ A, int lda, const ushort* __restrict__ Bt,
    const float* __restrict__ bias, void* __restrict__ Co, int N, int K) {
  constexpr int NT = BN / 64;  // N-subtiles per wave (2 for BN=128, 1 for BN=64)
  __shared__ ushort As[2][128 * 64];
  __shared__ ushort Bs[2][BN * 64];
  const int tid = threadIdx.x;
  const int lane = tid & 63, wid = tid >> 6;
  const int wm = wid >> 1, wn = wid & 1;
  const int l31 = lane & 31, hl = lane >> 5;
  const int bm = blockIdx.y * 128, bn = blockIdx.x * BN;

  f32x16 acc[2][NT];
#pragma unroll
  for (int mt = 0; mt < 2; ++mt)
#pragma unroll
    for (int nt = 0; nt < NT; ++nt)
#pragma unroll
      for (int r = 0; r < 16; ++r) acc[mt][nt][r] = 0.f;

  auto stage = [&](int buf, int k0) {
#pragma unroll
    for (int p = 0; p < 4; ++p) {
      const int v = tid + p * 256;
      const int r = v >> 3, sl = (v & 7) ^ (r & 7);
      gload_lds16(A + (size_t)(bm + r) * lda + k0 + sl * 8, &As[buf][v * 8]);
    }
#pragma unroll
    for (int p = 0; p < BN / 32; ++p) {
      const int v = tid + p * 256;
      const int r = v >> 3, sl = (v & 7) ^ (r & 7);
      gload_lds16(Bt + (size_t)(bn + r) * K + k0 + sl * 8, &Bs[buf][v * 8]);
    }
  };

  auto kstep = [&](int cbuf, int sbuf, int t, int nk) {
    if (t + 1 < nk) stage(sbuf, (t + 1) * 64);  // prefetch flies under compute
#pragma unroll
    for (int ks = 0; ks < 4; ++ks) {
      short8 af[2], bfr[NT];
      const int cb = ks * 32 + hl * 16;  // col-byte within 128B row
#pragma unroll
      for (int mt = 0; mt < 2; ++mt) {
        const int row = wm * 64 + mt * 32 + l31;
        af[mt] = *(const short8*)((const char*)&As[cbuf][0] + row * 128 +
                                  (cb ^ ((row & 7) << 4)));
      }
#pragma unroll
      for (int nt = 0; nt < NT; ++nt) {
        const int col = (BN == 128 ? wn * 64 + nt * 32 : wn * 32) + l31;
        bfr[nt] = *(const short8*)((const char*)&Bs[cbuf][0] + col * 128 +
                                   (cb ^ ((col & 7) << 4)));
      }
#pragma unroll
      for (int mt = 0; mt < 2; ++mt)
#pragma unroll
        for (int nt = 0; nt < NT; ++nt)
          acc[mt][nt] = __builtin_amdgcn_mfma_f32_32x32x16_bf16(af[mt], bfr[nt],
                                                                acc[mt][nt], 0, 0, 0);
    }
    __syncthreads();  // drains vmcnt(0): next buffer staged; all done reading cbuf
  };

  const int nk = K / 64;  // always even here
  stage(0, 0);
  __syncthreads();
  for (int t = 0; t < nk; t += 2) {
    kstep(0, 1, t, nk);
    kstep(1, 0, t + 1, nk);
  }

  // epilogue: C row=(r&3)+8*(r>>2)+4*hl (+32mt+64wm), col per BN mapping
  const float kinv = (RD != 0) ? (9.210340371976184f / (float)RD) : 0.f;
#pragma unroll
  for (int mt = 0; mt < 2; ++mt)
#pragma unroll
    for (int nt = 0; nt < NT; ++nt) {
      const int col = bn + (BN == 128 ? wn * 64 + nt * 32 : wn * 32) + l31;
      const float bi = bias ? bias[col] : 0.f;
      float th = 0.f;
      if constexpr (RD != 0) th = expf(-(float)(col >> 1) * kinv);
#pragma unroll
      for (int r = 0; r < 16; ++r) {
        const int row = bm + wm * 64 + mt * 32 + ((r & 3) + 8 * (r >> 2) + 4 * hl);
        float v = acc[mt][nt][r] + bi;
        if constexpr (RD != 0) {
          const int t = row & (TT - 1);
          float sn, cs;
          sincosf((float)(t + 1) * th, &sn, &cs);
          const float pv = __shfl_xor(v, 1);  // partner column (lane^1)
          v = (l31 & 1) ? (v * cs + pv * sn) : (v * cs - pv * sn);
        }
        if constexpr (OM == 2) v *= QSCALE;
        if constexpr (OM == 0)
          ((float*)Co)[(size_t)row * N + col] = v;
        else
          ((ushort*)Co)[(size_t)row * N + col] = bfu(v);
      }
    }
}

// ---------------------------------------------------------------------------
// MFMA flash attention. K/V prefetch: loads for kt+1 issued before compute(kt).
__global__ __launch_bounds__(256, 3) void flash_kernel(
    const ushort* __restrict__ qarr, const ushort* __restrict__ qRarr,
    const ushort* __restrict__ karr, const ushort* __restrict__ kRarr,
    const ushort* __restrict__ varr, ushort* __restrict__ oarr) {
  __shared__ ushort Ks[64][200];
  __shared__ ushort Vt[128][72];

  const int bi = (int)gridDim.x - 1 - (int)blockIdx.x;
  const int qt0 = bi * 128;
  const int bh = blockIdx.y;
  const int b = bh >> 4, hh = bh & 15;
  const int tid = threadIdx.x;
  const int lane = tid & 63, wid = tid >> 6;
  const int l31 = lane & 31, hl = lane >> 5;
  const int qbase = qt0 + wid * 32;
  const size_t rowbase = (size_t)b * TT;

  short8 qf[12];
  {
    const ushort* qp  = qarr  + (rowbase + qbase + l31) * 2048 + hh * 128;
    const ushort* qRp = qRarr + (rowbase + qbase + l31) * 1024 + hh * 64;
#pragma unroll
    for (int ks = 0; ks < 12; ++ks) {
      const int d = ks * 16 + hl * 8;
      const ushort* p = (d < 128) ? (qp + d) : (qRp + (d - 128));
      qf[ks] = *(const short8*)p;
    }
  }

  f32x16 oacc[4];
#pragma unroll
  for (int nt = 0; nt < 4; ++nt)
#pragma unroll
    for (int r = 0; r < 16; ++r) oacc[nt][r] = 0.f;
  float m_run = -1e30f, l_run = 0.f;

  short8 kreg[6], vreg[4];
  const int ldr = tid >> 2, lds4 = tid & 3;      // K staging coords
  const int vr = tid & 63, dblk = tid >> 6;      // V staging coords
  auto loadKV = [&](int kt0) {
    const ushort* kp  = karr  + (rowbase + kt0 + ldr) * 2048 + hh * 128;
    const ushort* kRp = kRarr + (rowbase + kt0 + ldr) * 64;
#pragma unroll
    for (int c = 0; c < 6; ++c) {
      const int d0 = c * 32 + lds4 * 8;
      const ushort* p = (d0 < 128) ? (kp + d0) : (kRp + (d0 - 128));
      kreg[c] = *(const short8*)p;
    }
    const ushort* vp = varr + (rowbase + kt0 + vr) * 2048 + hh * 128 + dblk * 32;
#pragma unroll
    for (int c = 0; c < 4; ++c) vreg[c] = *(const short8*)(vp + c * 8);
  };

  const int nkt = 2 * bi + 2;
  loadKV(0);  // prologue prefetch
  for (int kt = 0; kt < nkt; ++kt) {
    __syncthreads();  // all waves done reading LDS from previous iteration
    {
#pragma unroll
      for (int c = 0; c < 6; ++c) *(short8*)&Ks[ldr][c * 32 + lds4 * 8] = kreg[c];
#pragma unroll
      for (int c = 0; c < 4; ++c)
#pragma unroll
        for (int e = 0; e < 8; ++e)
          Vt[dblk * 32 + c * 8 + e][vr] = (ushort)vreg[c][e];
    }
    __syncthreads();
    if (kt + 1 < nkt) loadKV((kt + 1) * 64);  // flies under compute below

    const int kt0 = kt * 64;
    if (kt0 < qbase + 32) {
      f32x16 sa[2];
#pragma unroll
      for (int t2 = 0; t2 < 2; ++t2)
#pragma unroll
        for (int r = 0; r < 16; ++r) sa[t2][r] = 0.f;
      __builtin_amdgcn_s_setprio(1);
#pragma unroll
      for (int ks = 0; ks < 12; ++ks) {
        const short8 ka0 = *(const short8*)&Ks[l31][ks * 16 + hl * 8];
        const short8 ka1 = *(const short8*)&Ks[32 + l31][ks * 16 + hl * 8];
        sa[0] = __builtin_amdgcn_mfma_f32_32x32x16_bf16(ka0, qf[ks], sa[0], 0, 0, 0);
        sa[1] = __builtin_amdgcn_mfma_f32_32x32x16_bf16(ka1, qf[ks], sa[1], 0, 0, 0);
      }
      __builtin_amdgcn_s_setprio(0);
      if (kt0 + 63 > qbase) {
        const int qrow = qbase + l31;
#pragma unroll
        for (int t2 = 0; t2 < 2; ++t2)
#pragma unroll
          for (int r = 0; r < 16; ++r) {
            const int kcol = kt0 + t2 * 32 + (r & 3) + 8 * (r >> 2) + 4 * hl;
            if (kcol > qrow) sa[t2][r] = -1e30f;
          }
      }
      float pmax = -1e30f;
#pragma unroll
      for (int t2 = 0; t2 < 2; ++t2)
#pragma unroll
        for (int r = 0; r < 16; ++r) pmax = fmaxf(pmax, sa[t2][r]);
      pmax = fmaxf(pmax, __shfl_xor(pmax, 32));
      if (!__all(pmax <= m_run + 8.0f)) {  // defer-max (T13)
        const float mnew = fmaxf(m_run, pmax);
        const float alpha = __expf(m_run - mnew);
        m_run = mnew;
        l_run *= alpha;
#pragma unroll
        for (int r = 0; r < 16; ++r) {
          const int qr = (r & 3) + 8 * (r >> 2) + 4 * hl;
          const float al = __shfl(alpha, qr);
          oacc[0][r] *= al; oacc[1][r] *= al; oacc[2][r] *= al; oacc[3][r] *= al;
        }
      }
      float rsum = 0.f;
#pragma unroll
      for (int t2 = 0; t2 < 2; ++t2)
#pragma unroll
        for (int r = 0; r < 16; ++r) {
          const float p = __expf(sa[t2][r] - m_run);
          sa[t2][r] = p;
          rsum += p;
        }
      rsum += __shfl_xor(rsum, 32);
      l_run += rsum;
      short8 pf[4];
#pragma unroll
      for (int t2 = 0; t2 < 2; ++t2)
#pragma unroll
        for (int kb = 0; kb < 2; ++kb) {
          const int g = kb * 8;
          unsigned wa = pk2(sa[t2][g + 0], sa[t2][g + 1]);
          unsigned wb = pk2(sa[t2][g + 4], sa[t2][g + 5]);
          unsigned wc = pk2(sa[t2][g + 2], sa[t2][g + 3]);
          unsigned wd = pk2(sa[t2][g + 6], sa[t2][g + 7]);
          asm volatile("v_permlane32_swap_b32 %0, %1" : "+v"(wa), "+v"(wb));
          asm volatile("v_permlane32_swap_b32 %0, %1" : "+v"(wc), "+v"(wd));
          union { unsigned u[4]; short8 s; } cv;
          cv.u[0] = wa; cv.u[1] = wc; cv.u[2] = wb; cv.u[3] = wd;
          pf[t2 * 2 + kb] = cv.s;
        }
      __builtin_amdgcn_s_setprio(1);
#pragma unroll
      for (int ks = 0; ks < 4; ++ks)
#pragma unroll
        for (int nt = 0; nt < 4; ++nt) {
          const short8 vf = *(const short8*)&Vt[nt * 32 + l31][ks * 16 + hl * 8];
          oacc[nt] = __builtin_amdgcn_mfma_f32_32x32x16_bf16(pf[ks], vf, oacc[nt], 0, 0, 0);
        }
      __builtin_amdgcn_s_setprio(0);
    }
  }

  const float inv = 1.0f / l_run;
#pragma unroll
  for (int r = 0; r < 16; ++r) {
    const int qr = (r & 3) + 8 * (r >> 2) + 4 * hl;
    const float il = __shfl(inv, qr);
    ushort* orow = oarr + (rowbase + qbase + qr) * 2048 + hh * 128;
#pragma unroll
    for (int nt = 0; nt < 4; ++nt) orow[nt * 32 + l31] = bfu(oacc[nt][r] * il);
  }
}

// ---------------------------------------------------------------------------
extern "C" void kernel_launch(void* const* d_in, const int* in_sizes, int n_in,
                              void* d_out, int out_size, void* d_ws, size_t ws_size,
                              hipStream_t stream) {
  const float* x   = (const float*)d_in[0];
  const float* WA  = (const float*)d_in[1];
  const float* bA  = (const float*)d_in[2];
  const float* WB  = (const float*)d_in[3];
  const float* bB  = (const float*)d_in[4];
  const float* WC  = (const float*)d_in[5];
  const float* bC  = (const float*)d_in[6];
  const float* WUQ = (const float*)d_in[7];
  const float* WUK = (const float*)d_in[8];
  const float* WUV = (const float*)d_in[9];
  const float* WZ  = (const float*)d_in[10];
  const float* bZ  = (const float*)d_in[11];
  float* out = (float*)d_out;

  // workspace (ushorts), ~130 MB total
  ushort* xb   = (ushort*)d_ws;                 // 4096x2048
  ushort* WAt  = xb   + (size_t)MM * 2048;      // 1024x2048 (WA^T)
  ushort* WCt  = WAt  + (size_t)1024 * 2048;    // 1024x1024
  ushort* WUQt = WCt  + (size_t)1024 * 1024;    // 2048x512
  ushort* WUKt = WUQt + (size_t)2048 * 512;
  ushort* WUVt = WUKt + (size_t)2048 * 512;
  ushort* WZt  = WUVt + (size_t)2048 * 512;     // 2048x2048
  ushort* hb   = WZt  + (size_t)2048 * 2048;    // 4096x1024
  ushort* kR   = hb   + (size_t)MM * 1024;      // 4096x64
  ushort* qR   = kR   + (size_t)MM * 64;        // 4096x1024
  ushort* qb   = qR   + (size_t)MM * 1024;      // 4096x2048
  ushort* kb   = qb   + (size_t)MM * 2048;
  ushort* vb   = kb   + (size_t)MM * 2048;
  ushort* aob  = vb   + (size_t)MM * 2048;
  ushort* WBt  = aob  + (size_t)MM * 2048;      // 64x1024 (WB^T)

  const dim3 thr(256);

  // ---- prep: bf16 conversions (x flat; weights transposed to NxK)
  conv_kernel<<<dim3((MM * 2048) / 1024), thr, 0, stream>>>(x, xb);
  tconv_kernel<<<dim3(1024 / 64, 2048 / 64), thr, 0, stream>>>(WA, WAt, 2048, 1024);
  tconv_kernel<<<dim3(1024 / 64, 1024 / 64), thr, 0, stream>>>(WC, WCt, 1024, 1024);
  tconv_kernel<<<dim3(64 / 64, 1024 / 64), thr, 0, stream>>>(WB, WBt, 1024, 64);
  tconv_kernel<<<dim3(2048 / 64, 512 / 64), thr, 0, stream>>>(WUQ, WUQt, 512, 2048);
  tconv_kernel<<<dim3(2048 / 64, 512 / 64), thr, 0, stream>>>(WUK, WUKt, 512, 2048);
  tconv_kernel<<<dim3(2048 / 64, 512 / 64), thr, 0, stream>>>(WUV, WUVt, 512, 2048);
  tconv_kernel<<<dim3(2048 / 64, 2048 / 64), thr, 0, stream>>>(WZ, WZt, 2048, 2048);

  // ---- GEMMs (MFMA bf16, 2-phase pipelined)
  // h = x @ WA + bA -> bf16
  gemm_mfma_kernel<0, 1, 128><<<dim3(1024 / 128, MM / 128), thr, 0, stream>>>(
      xb, 2048, WAt, bA, hb, 1024, 2048);
  // kR = rope64(h @ WB + bB) -> bf16 (BN=64 MFMA)
  gemm_mfma_kernel<64, 1, 64><<<dim3(1, MM / 128), thr, 0, stream>>>(
      hb, 1024, WBt, bB, kR, 64, 1024);
  // qR = rope1024(h @ WC + bC) * qscale -> bf16
  gemm_mfma_kernel<1024, 2, 128><<<dim3(1024 / 128, MM / 128), thr, 0, stream>>>(
      hb, 1024, WCt, bC, qR, 1024, 1024);
  // q = (q_lat @ WUQ) * qscale -> bf16   (q_lat = h[:,512:])
  gemm_mfma_kernel<0, 2, 128><<<dim3(2048 / 128, MM / 128), thr, 0, stream>>>(
      hb + 512, 1024, WUQt, nullptr, qb, 2048, 512);
  // k = kv_lat @ WUK -> bf16
  gemm_mfma_kernel<0, 1, 128><<<dim3(2048 / 128, MM / 128), thr, 0, stream>>>(
      hb, 1024, WUKt, nullptr, kb, 2048, 512);
  // v = kv_lat @ WUV -> bf16
  gemm_mfma_kernel<0, 1, 128><<<dim3(2048 / 128, MM / 128), thr, 0, stream>>>(
      hb, 1024, WUVt, nullptr, vb, 2048, 512);
  // ---- flash attention -> ao bf16
  flash_kernel<<<dim3(TT / 128, BB * NHH), thr, 0, stream>>>(qb, qR, kb, kR, vb, aob);
  // ---- out = ao @ WZ + bZ -> fp32
  gemm_mfma_kernel<0, 0, 128><<<dim3(2048 / 128, MM / 128), thr, 0, stream>>>(
      aob, 2048, WZt, bZ, out, 2048, 2048);
}